// Round 4
// baseline (676.598 us; speedup 1.0000x reference)
//
#include <hip/hip_runtime.h>
#include <hip/hip_bf16.h>
#include <math.h>

typedef __bf16 bf16_t;
typedef __bf16 bf16x4_t __attribute__((ext_vector_type(4)));
typedef __bf16 bf16x8_t __attribute__((ext_vector_type(8)));
typedef float  f32x4_t  __attribute__((ext_vector_type(4)));

#define N_TOK 4096
#define D_IN  4096
#define O_OUT 4096
#define NEXP  8
#define NHEAD 3
#define RANK  16
#define KC2   384
#define PCOLS 256
#define SCALING_F 2.0f
#define NBLK  512          // persistent grid: 2 blocks/CU, co-resident (LDS cap = 5/CU)
#define SPLITK 8

// ---------------- device-scope grid barrier (all NBLK blocks co-resident) ----------------
__device__ __forceinline__ void grid_barrier(unsigned* cnt, unsigned* gen) {
  __syncthreads();
  if (threadIdx.x == 0) {
    __threadfence();  // agent-scope release of this block's prior writes
    unsigned old = __hip_atomic_fetch_add(cnt, 1u, __ATOMIC_ACQ_REL, __HIP_MEMORY_SCOPE_AGENT);
    if (old == NBLK - 1) {
      __hip_atomic_store(gen, 1u, __ATOMIC_RELEASE, __HIP_MEMORY_SCOPE_AGENT);
    } else {
      while (!__hip_atomic_load(gen, __ATOMIC_ACQUIRE, __HIP_MEMORY_SCOPE_AGENT))
        __builtin_amdgcn_s_sleep(8);
    }
    __threadfence();  // agent-scope acquire before this block's subsequent reads
  }
  __syncthreads();
}

// ---------------- 64x64 transpose tile fp32 -> bf16 (syncs fore+aft internally) ----------------
__device__ __forceinline__ void transpose_tile(const float* __restrict__ src,
                                               bf16_t* __restrict__ dst,
                                               int Rr, int Cc, int r0, int c0,
                                               float (*tile)[65]) {
  int q  = threadIdx.x & 15;
  int r4 = threadIdx.x >> 4;
  #pragma unroll
  for (int g = 0; g < 4; ++g) {
    int r = r4 + g * 16;
    float4 v = *(const float4*)(src + (size_t)(r0 + r) * Cc + c0 + q * 4);
    tile[r][q * 4 + 0] = v.x; tile[r][q * 4 + 1] = v.y;
    tile[r][q * 4 + 2] = v.z; tile[r][q * 4 + 3] = v.w;
  }
  __syncthreads();
  #pragma unroll
  for (int g = 0; g < 4; ++g) {
    int c = r4 + g * 16;
    bf16x4_t o = { (bf16_t)tile[q * 4 + 0][c], (bf16_t)tile[q * 4 + 1][c],
                   (bf16_t)tile[q * 4 + 2][c], (bf16_t)tile[q * 4 + 3][c] };
    *(bf16x4_t*)(dst + (size_t)(c0 + c) * Rr + r0 + q * 4) = o;
  }
  __syncthreads();  // safe LDS reuse by next tile
}

// ---------------- m97-style MFMA K-loop (0 bank conflicts verified R1-R3) ----------------
__device__ __forceinline__ void run_kloop(f32x4_t (&acc)[4][4], bf16_t* sA, bf16_t* sB,
                                          const bf16_t* __restrict__ Ab, int lda,
                                          const bf16_t* __restrict__ Bb, int ldb, int K) {
  const int tid = threadIdx.x;
  const int lane = tid & 63;
  const int w = tid >> 6;
  const int wm = (w >> 1) * 64;
  const int wn = (w & 1) * 64;
  const int qd = lane >> 4;
  const int ln = lane & 15;
  const int sw = ln & 7;

  size_t offA[4], offB[4];
  int lo[4];
  #pragma unroll
  for (int t = 0; t < 4; ++t) {
    int c = tid + t * 256;
    int m = c >> 3, kc = (c & 7) ^ (m & 7);
    offA[t] = (size_t)m * lda + kc * 8;
    offB[t] = (size_t)m * ldb + kc * 8;
    lo[t] = c * 8;
  }
  int rowA[4], rowB[4];
  #pragma unroll
  for (int i = 0; i < 4; ++i) {
    rowA[i] = (wm + i * 16 + ln) * 64;
    rowB[i] = (wn + i * 16 + ln) * 64;
  }

  for (int k0 = 0; k0 < K; k0 += 64) {
    __syncthreads();
    #pragma unroll
    for (int t = 0; t < 4; ++t)
      __builtin_amdgcn_global_load_lds(
          (const __attribute__((address_space(1))) void*)(Ab + k0 + offA[t]),
          (__attribute__((address_space(3))) void*)(sA + lo[t]), 16, 0, 0);
    #pragma unroll
    for (int t = 0; t < 4; ++t)
      __builtin_amdgcn_global_load_lds(
          (const __attribute__((address_space(1))) void*)(Bb + k0 + offB[t]),
          (__attribute__((address_space(3))) void*)(sB + lo[t]), 16, 0, 0);
    __syncthreads();
    #pragma unroll
    for (int s = 0; s < 2; ++s) {
      bf16x8_t af[4], bfr[4];
      int kx = ((s * 4 + qd) ^ sw) * 8;
      #pragma unroll
      for (int i = 0; i < 4; ++i) af[i]  = *(const bf16x8_t*)(sA + rowA[i] + kx);
      #pragma unroll
      for (int i = 0; i < 4; ++i) bfr[i] = *(const bf16x8_t*)(sB + rowB[i] + kx);
      #pragma unroll
      for (int i = 0; i < 4; ++i)
        #pragma unroll
        for (int j = 0; j < 4; ++j)
          acc[i][j] = __builtin_amdgcn_mfma_f32_16x16x32_bf16(af[i], bfr[j], acc[i][j], 0, 0, 0);
    }
  }
}

// ---------------- the whole pipeline as ONE persistent kernel ----------------
__global__ __launch_bounds__(256) void mono_kernel(const float* __restrict__ x,
                                                   const float* __restrict__ base_W,
                                                   const float* __restrict__ rw,
                                                   const float* __restrict__ A,
                                                   const float* __restrict__ B,
                                                   const float* __restrict__ Rm,
                                                   bf16_t* __restrict__ xb,
                                                   bf16_t* __restrict__ WbT,
                                                   bf16_t* __restrict__ BbT,
                                                   bf16_t* __restrict__ PabT,
                                                   bf16_t* __restrict__ C2b,
                                                   int* __restrict__ gidx,
                                                   float* __restrict__ gwv,
                                                   float* __restrict__ projP,
                                                   float* __restrict__ out,
                                                   unsigned* __restrict__ bar) {
  __shared__ __align__(16) char smem[32768];
  float (*tile)[65] = (float(*)[65])smem;
  bf16_t* sA = (bf16_t*)smem;
  bf16_t* sB = (bf16_t*)(smem + 16384);
  const int blk = blockIdx.x;
  const int tid = threadIdx.x;

  // ========== phase 1: prep (transposes/cvt/router/pack) ==========
  // W transpose: 4096 tiles, 8 per block
  #pragma unroll
  for (int i = 0; i < 8; ++i) {
    int t = blk * 8 + i;
    transpose_tile(base_W, WbT, 4096, 4096, (t & 63) * 64, (t >> 6) * 64, tile);
  }
  // B transpose: 384 tiles over blocks [0,384)
  if (blk < 384) transpose_tile(B, BbT, KC2, 4096, (blk % 6) * 64, (blk / 6) * 64, tile);
  // pack A/R -> PabT: 256 columns over blocks [0,256)
  if (blk < 256) {
    int c = blk;
    for (int d = tid; d < D_IN; d += 256) {
      float v = 0.f;
      if (c < 128) {
        int e = c >> 4, r = c & 15;
        v = A[((size_t)e * D_IN + d) * RANK + r];
      } else if (c < 152) {
        int qq = c - 128; int e = qq / 3, h = qq - 3 * e;
        v = Rm[((size_t)e * D_IN + d) * NHEAD + h];
      }
      PabT[(size_t)c * D_IN + d] = (bf16_t)v;
    }
  }
  // cvt x -> bf16 + exact fp32 top-2 router: 8 tokens per block (1/wave, 2 rounds)
  {
    int lane = tid & 63;
    int wv = tid >> 6;
    #pragma unroll
    for (int it = 0; it < 2; ++it) {
      int n = blk * 8 + it * 4 + wv;
      const float4* xv = (const float4*)(x + (size_t)n * D_IN);
      bf16x4_t* xo = (bf16x4_t*)(xb + (size_t)n * D_IN);
      float acc[NEXP] = {0, 0, 0, 0, 0, 0, 0, 0};
      for (int d = lane; d < D_IN / 4; d += 64) {
        float4 xx = xv[d];
        bf16x4_t ob = { (bf16_t)xx.x, (bf16_t)xx.y, (bf16_t)xx.z, (bf16_t)xx.w };
        xo[d] = ob;
        #pragma unroll
        for (int e = 0; e < NEXP; ++e) {
          float4 ww = ((const float4*)(rw + (size_t)e * D_IN))[d];
          acc[e] += xx.x * ww.x + xx.y * ww.y + xx.z * ww.z + xx.w * ww.w;
        }
      }
      #pragma unroll
      for (int e = 0; e < NEXP; ++e) {
        float v = acc[e];
        #pragma unroll
        for (int o = 32; o > 0; o >>= 1) v += __shfl_down(v, o);
        acc[e] = v;
      }
      if (lane == 0) {
        int i0 = 0; float l0 = acc[0];
        #pragma unroll
        for (int e = 1; e < NEXP; ++e) if (acc[e] > l0) { l0 = acc[e]; i0 = e; }
        int i1 = -1; float l1 = -3.4e38f;
        #pragma unroll
        for (int e = 0; e < NEXP; ++e) if (e != i0 && acc[e] > l1) { l1 = acc[e]; i1 = e; }
        float w0 = 1.f / (1.f + expf(l1 - l0));
        gidx[2 * n] = i0; gidx[2 * n + 1] = i1;
        gwv[2 * n] = w0;  gwv[2 * n + 1] = 1.f - w0;
      }
    }
  }

  grid_barrier(bar + 0, bar + 1);

  // ========== phase 2: proj split-K GEMM (K=512 slices, partials to projP) ==========
  {
    int kz = blk >> 6;             // 0..7
    int rem = blk & 63;
    int bm = rem >> 1, bn = rem & 1;
    f32x4_t acc[4][4] = {};
    run_kloop(acc, sA, sB,
              xb + (size_t)bm * 128 * D_IN + kz * 512, D_IN,
              PabT + (size_t)bn * 128 * D_IN + kz * 512, D_IN, 512);
    const int lane = tid & 63, w = tid >> 6;
    const int wm = (w >> 1) * 64, wn = (w & 1) * 64, qd = lane >> 4, ln = lane & 15;
    float* Cb = projP + (size_t)kz * N_TOK * PCOLS + (size_t)bm * 128 * PCOLS + bn * 128;
    #pragma unroll
    for (int i = 0; i < 4; ++i)
      #pragma unroll
      for (int j = 0; j < 4; ++j) {
        int col = wn + j * 16 + ln;
        #pragma unroll
        for (int rg = 0; rg < 4; ++rg)
          Cb[(size_t)(wm + i * 16 + qd * 4 + rg) * PCOLS + col] = acc[i][j][rg];
      }
  }

  grid_barrier(bar + 2, bar + 3);

  // ========== phase 3: gating -> C2b (sum SPLITK partials) ==========
  {
    const size_t S = (size_t)N_TOK * PCOLS;
    for (int tt = 0; tt < 8; ++tt) {
      int n = blk * 8 + tt;
      int i0 = gidx[2 * n], i1 = gidx[2 * n + 1];
      float g0 = gwv[2 * n], g1 = gwv[2 * n + 1];
      const float* p0 = projP + (size_t)n * PCOLS;
      for (int c = tid; c < KC2; c += 256) {
        int e = c / 48;
        int h = (c % 48) / 16;
        int r = c & 15;
        float g = (e == i0) ? g0 : (e == i1) ? g1 : 0.f;
        float val = 0.f;
        if (g != 0.f) {
          float h0 = 0.f, h1 = 0.f, h2 = 0.f, av = 0.f;
          #pragma unroll
          for (int p = 0; p < SPLITK; ++p) {
            const float* pp = p0 + p * S;
            h0 += pp[128 + e * 3 + 0];
            h1 += pp[128 + e * 3 + 1];
            h2 += pp[128 + e * 3 + 2];
            av += pp[e * 16 + r];
          }
          float mx = fmaxf(h0, fmaxf(h1, h2));
          float e0 = expf(h0 - mx), e1 = expf(h1 - mx), e2 = expf(h2 - mx);
          float hw = (h == 0 ? e0 : h == 1 ? e1 : e2) / (e0 + e1 + e2);
          val = SCALING_F * g * hw * av;
        }
        C2b[(size_t)n * KC2 + c] = (bf16_t)val;
      }
    }
  }

  grid_barrier(bar + 4, bar + 5);

  // ========== phase 4: fused base+delta GEMM, 2 tiles per block ==========
  {
    int bm = blk & 31;
    int bnp = (blk >> 5) * 2;
    for (int t = 0; t < 2; ++t) {
      int bn = bnp + t;
      f32x4_t acc[4][4] = {};
      run_kloop(acc, sA, sB,
                xb + (size_t)bm * 128 * D_IN, D_IN,
                WbT + (size_t)bn * 128 * D_IN, D_IN, D_IN);
      run_kloop(acc, sA, sB,
                C2b + (size_t)bm * 128 * KC2, KC2,
                BbT + (size_t)bn * 128 * KC2, KC2, KC2);
      const int lane = tid & 63, w = tid >> 6;
      const int wm = (w >> 1) * 64, wn = (w & 1) * 64, qd = lane >> 4, ln = lane & 15;
      float* Cb = out + (size_t)bm * 128 * O_OUT + bn * 128;
      #pragma unroll
      for (int i = 0; i < 4; ++i)
        #pragma unroll
        for (int j = 0; j < 4; ++j) {
          int col = wn + j * 16 + ln;
          #pragma unroll
          for (int rg = 0; rg < 4; ++rg)
            Cb[(size_t)(wm + i * 16 + qd * 4 + rg) * O_OUT + col] = acc[i][j][rg];
        }
      __syncthreads();  // LDS safe before next tile
    }
  }
}

// ---------------- launch ----------------
// ws layout (bytes):
//   xb    @ 0         : 33554432
//   WbT   @ 33554432  : 33554432
//   PabT  @ 67108864  : 2097152
//   BbT   @ 69206016  : 3145728
//   C2b   @ 72351744  : 3145728
//   gidx  @ 75497472  : 32768
//   gwv   @ 75530240  : 32768
//   bar   @ 75563008  : 64
// projP [8][4096][256] fp32 (33.5 MB) lives in d_out (dead until phase 4 overwrites).
extern "C" void kernel_launch(void* const* d_in, const int* in_sizes, int n_in,
                              void* d_out, int out_size, void* d_ws, size_t ws_size,
                              hipStream_t stream) {
  const float* x       = (const float*)d_in[0];
  const float* base_W  = (const float*)d_in[1];
  const float* routerW = (const float*)d_in[2];
  const float* A       = (const float*)d_in[3];
  const float* B       = (const float*)d_in[4];
  const float* Rm      = (const float*)d_in[5];
  float* out = (float*)d_out;
  char* ws = (char*)d_ws;

  bf16_t* xb   = (bf16_t*)(ws);
  bf16_t* WbT  = (bf16_t*)(ws + 33554432);
  bf16_t* PabT = (bf16_t*)(ws + 67108864);
  bf16_t* BbT  = (bf16_t*)(ws + 69206016);
  bf16_t* C2b  = (bf16_t*)(ws + 72351744);
  int*    gidx = (int*)   (ws + 75497472);
  float*  gwv  = (float*) (ws + 75530240);
  unsigned* bar = (unsigned*)(ws + 75563008);
  float* projP = out;

  hipMemsetAsync(bar, 0, 64, stream);
  mono_kernel<<<NBLK, 256, 0, stream>>>(x, base_W, routerW, A, B, Rm,
                                        xb, WbT, BbT, PabT, C2b, gidx, gwv,
                                        projP, out, bar);
}